// Round 7
// baseline (614839.893 us; speedup 1.0000x reference)
//
#include <hip/hip_runtime.h>
#include <hip/hip_bf16.h>
#include <stdint.h>

// ============================================================================
// 2-layer GRU, persistent kernel — ROUND 7: fp32 OUTPUT (the R1-R6 bug).
//   B=64, S=1024, I=256, H=1024, O=256, L=2
// R6 shadow-state proved the computation + input mapping faithful; the
// mismatch magnitude (0.9436 > 2*max|ref_y|=0.746) is only explainable by
// bf16 writes into an fp32 d_out (harness spec: reference output dtype fp32
// -> d_out is float*). This round: identical R2 pipeline, fp32 outputs.
// Phases per step t (monotonic device-wide barrier between all):
//   P1: z0, r0 (x(t), h0cur) + y(t-1) (h1cur)
//   P2: g0 + h0 update -> h0next
//   P3: z1, r1 (h0next, h1cur)
//   P4: g1 + h1 update -> h1next
// ============================================================================

#define NWG 192
#define TPB 256

constexpr int Bc = 64, Sc = 1024, Ic = 256, Hc = 1024, Oc = 256;
constexpr int64_t XRS = (int64_t)Sc * Ic;  // x batch-row stride

struct GruArgs {
  const float *x;
  const float *h0in;
  const float *Wxz0, *Wxr0, *Wxg0, *Whz0, *bhz0, *Whr0, *bhr0, *Whg0, *bhg0;
  const float *Wxz1, *Wxr1, *Wxg1, *Whz1, *bhz1, *Whr1, *bhr1, *Whg1, *bhg1;
  const float *WY, *bY;
  float *h0a, *h0b, *h1a, *h1b, *z0, *r0, *z1, *r1;
  unsigned *bar;
  float *y, *hs;   // fp32 outputs
};

__device__ __forceinline__ float sigm(float x) { return 1.0f / (1.0f + expf(-x)); }

// Monotonic device-wide barrier; bar[0] memset to 0 at launch.
__device__ void gbar(unsigned *bar, unsigned rnd)
{
  __syncthreads();
  __threadfence();
  if (threadIdx.x == 0) {
    __hip_atomic_fetch_add(bar, 1u, __ATOMIC_SEQ_CST, __HIP_MEMORY_SCOPE_AGENT);
    while (__hip_atomic_load(bar, __ATOMIC_SEQ_CST, __HIP_MEMORY_SCOPE_AGENT) < rnd * (unsigned)NWG)
      __builtin_amdgcn_s_sleep(2);
  }
  __syncthreads();
  __threadfence();
}

// OUT[64 x 16] += A[64 x K] @ W[K x 16], cols [cbase, cbase+16).
__device__ void accum_src(float acc[2][2],
                          const float *__restrict__ A, int64_t arst,
                          const float *__restrict__ R,
                          const float *__restrict__ W, int ldw, int K, int cbase,
                          float *Alds, float *Wlds)
{
  const int tid = threadIdx.x;
  const int rr = tid & 31;
  const int cc = (tid >> 5) << 1;
  for (int kc = 0; kc < K; kc += 64) {
    __syncthreads();
#pragma unroll
    for (int i = 0; i < 4; ++i) {
      int f = tid + i * TPB;
      int row = f >> 4;
      int ks = (f & 15) << 2;
      float4 v = *(const float4 *)(A + (int64_t)row * arst + kc + ks);
      if (R) {
        float4 rv = *(const float4 *)(R + row * Hc + kc + ks);
        v.x *= rv.x; v.y *= rv.y; v.z *= rv.z; v.w *= rv.w;
      }
      float *d = Alds + row * 65 + ks;
      d[0] = v.x; d[1] = v.y; d[2] = v.z; d[3] = v.w;
    }
    {
      int krow = tid >> 2;
      int cs = (tid & 3) << 2;
      float4 wv = *(const float4 *)(W + (int64_t)(kc + krow) * ldw + cbase + cs);
      *(float4 *)(Wlds + krow * 16 + cs) = wv;
    }
    __syncthreads();
#pragma unroll 16
    for (int kk = 0; kk < 64; ++kk) {
      float a0 = Alds[rr * 65 + kk];
      float a1 = Alds[(rr + 32) * 65 + kk];
      float2 wv = *(const float2 *)(Wlds + kk * 16 + cc);
      acc[0][0] = fmaf(a0, wv.x, acc[0][0]);
      acc[0][1] = fmaf(a0, wv.y, acc[0][1]);
      acc[1][0] = fmaf(a1, wv.x, acc[1][0]);
      acc[1][1] = fmaf(a1, wv.y, acc[1][1]);
    }
  }
}

__device__ void task_zr(const float *A1, int64_t a1rst, int K1, const float *Wx,
                        const float *h, const float *Wh, const float *bh,
                        int cbase, float *out, float *Alds, float *Wlds)
{
  const int tid = threadIdx.x;
  const int rr = tid & 31;
  const int cc = (tid >> 5) << 1;
  float b0 = bh[cbase + cc], b1 = bh[cbase + cc + 1];
  float acc[2][2] = {{b0, b1}, {b0, b1}};
  accum_src(acc, A1, a1rst, nullptr, Wx, Hc, K1, cbase, Alds, Wlds);
  accum_src(acc, h, Hc, nullptr, Wh, Hc, Hc, cbase, Alds, Wlds);
  out[rr * Hc + cbase + cc]            = sigm(acc[0][0]);
  out[rr * Hc + cbase + cc + 1]        = sigm(acc[0][1]);
  out[(rr + 32) * Hc + cbase + cc]     = sigm(acc[1][0]);
  out[(rr + 32) * Hc + cbase + cc + 1] = sigm(acc[1][1]);
}

__device__ void task_g(const float *A1, int64_t a1rst, int K1, const float *Wx,
                       const float *h, const float *rgate, const float *Wh, const float *bh,
                       const float *z, float *hnew,
                       int cbase, float *Alds, float *Wlds)
{
  const int tid = threadIdx.x;
  const int rr = tid & 31;
  const int cc = (tid >> 5) << 1;
  float b0 = bh[cbase + cc], b1 = bh[cbase + cc + 1];
  float acc[2][2] = {{b0, b1}, {b0, b1}};
  accum_src(acc, A1, a1rst, nullptr, Wx, Hc, K1, cbase, Alds, Wlds);
  accum_src(acc, h, Hc, rgate, Wh, Hc, Hc, cbase, Alds, Wlds);
#pragma unroll
  for (int i = 0; i < 2; ++i) {
    int row = rr + i * 32;
#pragma unroll
    for (int j = 0; j < 2; ++j) {
      int col = cbase + cc + j;
      float gv = tanhf(acc[i][j]);
      float zv = z[row * Hc + col];
      float ho = h[row * Hc + col];
      hnew[row * Hc + col] = zv * ho + (1.0f - zv) * gv;
    }
  }
}

__device__ void task_y(const float *h1, const float *WY, const float *bY,
                       int t, int cbase, float *y, float *Alds, float *Wlds)
{
  const int tid = threadIdx.x;
  const int rr = tid & 31;
  const int cc = (tid >> 5) << 1;
  float b0 = bY[cbase + cc], b1 = bY[cbase + cc + 1];
  float acc[2][2] = {{b0, b1}, {b0, b1}};
  accum_src(acc, h1, Hc, nullptr, WY, Oc, Hc, cbase, Alds, Wlds);
#pragma unroll
  for (int i = 0; i < 2; ++i) {
    int row = rr + i * 32;
#pragma unroll
    for (int j = 0; j < 2; ++j) {
      int col = cbase + cc + j;
      y[((int64_t)row * Sc + t) * Oc + col] = acc[i][j];
    }
  }
}

__global__ void __launch_bounds__(TPB) gru_persistent(GruArgs a)
{
  __shared__ float Alds[64 * 65];
  __shared__ float Wlds[64 * 16];
  const int wg = blockIdx.x;
  const int tid = threadIdx.x;
  unsigned rnd = 0;
  float *h0buf[2] = {a.h0a, a.h0b};
  float *h1buf[2] = {a.h1a, a.h1b};

  // init: h buffers <- h0 input [B, L=2, H]
  for (int i = wg * TPB + tid; i < Bc * Hc; i += NWG * TPB) {
    int b = i >> 10, h = i & (Hc - 1);
    a.h0a[i] = a.h0in[(b * 2 + 0) * Hc + h];
    a.h1a[i] = a.h0in[(b * 2 + 1) * Hc + h];
  }
  gbar(a.bar, ++rnd);

  for (int t = 0; t < Sc; ++t) {
    const int cur = t & 1, nxt = cur ^ 1;
    const float *xt = a.x + (int64_t)t * Ic;
    const float *h0c = h0buf[cur];
    float *h0n = h0buf[nxt];
    const float *h1c = h1buf[cur];
    float *h1n = h1buf[nxt];

    // P1: z0, r0, y(t-1)
    if (wg < 64)
      task_zr(xt, XRS, Ic, a.Wxz0, h0c, a.Whz0, a.bhz0, wg * 16, a.z0, Alds, Wlds);
    else if (wg < 128)
      task_zr(xt, XRS, Ic, a.Wxr0, h0c, a.Whr0, a.bhr0, (wg - 64) * 16, a.r0, Alds, Wlds);
    else if (t > 0 && wg < 144)
      task_y(h1c, a.WY, a.bY, t - 1, (wg - 128) * 16, a.y, Alds, Wlds);
    gbar(a.bar, ++rnd);

    // P2: g0 + h0 update
    if (wg < 64)
      task_g(xt, XRS, Ic, a.Wxg0, h0c, a.r0, a.Whg0, a.bhg0, a.z0, h0n, wg * 16, Alds, Wlds);
    gbar(a.bar, ++rnd);

    // P3: z1, r1
    if (wg < 64)
      task_zr(h0n, Hc, Hc, a.Wxz1, h1c, a.Whz1, a.bhz1, wg * 16, a.z1, Alds, Wlds);
    else if (wg < 128)
      task_zr(h0n, Hc, Hc, a.Wxr1, h1c, a.Whr1, a.bhr1, (wg - 64) * 16, a.r1, Alds, Wlds);
    gbar(a.bar, ++rnd);

    // P4: g1 + h1 update
    if (wg < 64)
      task_g(h0n, Hc, Hc, a.Wxg1, h1c, a.r1, a.Whg1, a.bhg1, a.z1, h1n, wg * 16, Alds, Wlds);
    gbar(a.bar, ++rnd);
  }

  // epilogue: y(S-1) from final h1 (slot 0: S even), hidden_state [B,L,H] fp32.
  if (wg < 16)
    task_y(a.h1a, a.WY, a.bY, Sc - 1, wg * 16, a.y, Alds, Wlds);
  else if (wg < 48) {
    for (int k = (wg - 16) * TPB + tid; k < Bc * 2 * Hc; k += 32 * TPB) {
      int b = k >> 11, l = (k >> 10) & 1, h = k & (Hc - 1);
      a.hs[k] = (l ? a.h1a : a.h0a)[b * Hc + h];
    }
  }
}

extern "C" void kernel_launch(void *const *d_in, const int *in_sizes, int n_in,
                              void *d_out, int out_size, void *d_ws, size_t ws_size,
                              hipStream_t stream)
{
  (void)in_sizes; (void)n_in; (void)out_size; (void)ws_size;
  GruArgs a;
  a.x    = (const float *)d_in[0];
  a.h0in = (const float *)d_in[1];
  a.Wxz0 = (const float *)d_in[2];
  a.Wxr0 = (const float *)d_in[3];
  a.Wxg0 = (const float *)d_in[4];
  a.Whz0 = (const float *)d_in[5];
  a.bhz0 = (const float *)d_in[6];
  a.Whr0 = (const float *)d_in[7];
  a.bhr0 = (const float *)d_in[8];
  a.Whg0 = (const float *)d_in[9];
  a.bhg0 = (const float *)d_in[10];
  a.Wxz1 = (const float *)d_in[11];
  a.Wxr1 = (const float *)d_in[12];
  a.Wxg1 = (const float *)d_in[13];
  a.Whz1 = (const float *)d_in[14];
  a.bhz1 = (const float *)d_in[15];
  a.Whr1 = (const float *)d_in[16];
  a.bhr1 = (const float *)d_in[17];
  a.Whg1 = (const float *)d_in[18];
  a.bhg1 = (const float *)d_in[19];
  a.WY   = (const float *)d_in[20];
  a.bY   = (const float *)d_in[21];

  float *w = (float *)d_ws;
  a.h0a = w;            a.h0b = w + 65536;
  a.h1a = w + 131072;   a.h1b = w + 196608;
  a.z0  = w + 262144;   a.r0  = w + 327680;
  a.z1  = w + 393216;   a.r1  = w + 458752;
  a.bar = (unsigned *)(w + 524288);
  a.y   = (float *)d_out;
  a.hs  = a.y + (int64_t)Bc * Sc * Oc;

  hipMemsetAsync(a.bar, 0, 256, stream);
  gru_persistent<<<NWG, TPB, 0, stream>>>(a);
}

// Round 8
// 76486.865 us; speedup vs baseline: 8.0385x; 8.0385x over previous
//
#include <hip/hip_runtime.h>
#include <hip/hip_bf16.h>
#include <stdint.h>

// ============================================================================
// 2-layer GRU — ROUND 8: MFMA + LDS-resident weights + relaxed LLC barrier.
//   B=64, S=1024, I=256, H=1024, O=256, L=2
// 200 persistent WGs with FIXED roles (weights packed bf16 into LDS once):
//   role 0: z0 (WG 0-31, 32 cols each)   role 3: z1 (96-127)
//   role 1: r0 (32-63)                   role 4: r1 (128-159)
//   role 2: g0 (64-95)                   role 5: g1 (160-191)
//   role 6: y  (192-199)
// 3 barriers/step: PA{g0+h0', y(t-1)} PB{z1,r1; z0,r0(t+1)} PC{g1+h1'}.
// Cross-WG state (h,z,r bf16) via relaxed AGENT atomics (LLC-coherent, no
// L2-invalidating fences). Two-level monotonic barrier (25 groups of 8).
// MFMA 16x16x32 bf16, fp32 accumulate; A-frags loaded per-lane from global,
// B-frags (weights) pre-packed in LDS in fragment order.
// ============================================================================

#define NWG 200
#define TPB 256
#define NGRP 25
#define KB 8

typedef unsigned long long u64;
typedef __attribute__((ext_vector_type(8))) short bfrag;
typedef __attribute__((ext_vector_type(4))) float f32x4;

constexpr int Bc = 64, Sc = 1024, Ic = 256, Hc = 1024, Oc = 256;

struct Args {
  const float *x, *h0in;
  const float *W1[7], *W2[7], *bias[7];
  unsigned short *h0a, *h0b, *h1a, *h1b, *z0, *r0, *z1, *r1;
  unsigned *bar;
  float *y, *hs;
};

// ---------------- atomic helpers (agent scope = LLC-coherent) ---------------
__device__ __forceinline__ u64 ald64(const void *p) {
  return __hip_atomic_load((const u64 *)p, __ATOMIC_RELAXED, __HIP_MEMORY_SCOPE_AGENT);
}
__device__ __forceinline__ unsigned ald32(const void *p) {
  return __hip_atomic_load((const unsigned *)p, __ATOMIC_RELAXED, __HIP_MEMORY_SCOPE_AGENT);
}
__device__ __forceinline__ void ast32(void *p, unsigned v) {
  __hip_atomic_store((unsigned *)p, v, __ATOMIC_RELAXED, __HIP_MEMORY_SCOPE_AGENT);
}
__device__ __forceinline__ unsigned short f2b(float x) {
  __hip_bfloat16 b = __float2bfloat16(x);
  return __builtin_bit_cast(unsigned short, b);
}
__device__ __forceinline__ float b2f(unsigned short u) {
  return __uint_as_float(((unsigned)u) << 16);
}

// ---------------- two-level monotonic barrier (leader thread only) ----------
__device__ void gbar(unsigned *bar, unsigned rnd, int wg) {
  __syncthreads();                       // drains vmcnt: all WG stores LLC-acked
  if (threadIdx.x == 0) {
    int g = wg >> 3;                     // 25 groups of exactly 8
    unsigned a = __hip_atomic_fetch_add(bar + 32 + g * 32, 1u,
                                        __ATOMIC_RELAXED, __HIP_MEMORY_SCOPE_AGENT);
    if (a + 1u == rnd * 8u)
      __hip_atomic_fetch_add(bar, 1u, __ATOMIC_RELAXED, __HIP_MEMORY_SCOPE_AGENT);
    while (__hip_atomic_load(bar, __ATOMIC_RELAXED, __HIP_MEMORY_SCOPE_AGENT) < rnd * NGRP)
      __builtin_amdgcn_s_sleep(1);
  }
  __syncthreads();
}

// ---------------- MFMA segments (per wave; rows rbase..rbase+15) ------------
// A-frag: lane holds A[rbase + (lane&15)][k0 + (lane>>4)*8 + j], j=0..7.
// B-frag (LDS): slot ((ks*2+nt)*64 + lane)*8 shorts.
__device__ void seg_h(f32x4 *acc, const unsigned short *hb, const short *wl,
                      int nkoff, int NK, int lane, int rbase) {
  const u64 *ap = (const u64 *)(hb + (size_t)(rbase + (lane & 15)) * Hc) + (lane >> 4) * 2;
  for (int ks = 0; ks < NK; ks += KB) {
    u64 av[2 * KB];
#pragma unroll
    for (int q = 0; q < KB; ++q) {
      av[2 * q]     = ald64(ap + (size_t)(ks + q) * 8);
      av[2 * q + 1] = ald64(ap + (size_t)(ks + q) * 8 + 1);
    }
#pragma unroll
    for (int q = 0; q < KB; ++q) {
      union { u64 u[2]; bfrag v; } cc;
      cc.u[0] = av[2 * q]; cc.u[1] = av[2 * q + 1];
      const short *wp = wl + (((size_t)(nkoff + ks + q) * 2) * 64 + lane) * 8;
      acc[0] = __builtin_amdgcn_mfma_f32_16x16x32_bf16(cc.v, *(const bfrag *)wp, acc[0], 0, 0, 0);
      acc[1] = __builtin_amdgcn_mfma_f32_16x16x32_bf16(cc.v, *(const bfrag *)(wp + 512), acc[1], 0, 0, 0);
    }
  }
}

__device__ void seg_rh(f32x4 *acc, const unsigned short *hb, const unsigned short *rb,
                       const short *wl, int nkoff, int NK, int lane, int rbase) {
  size_t ro = (size_t)(rbase + (lane & 15)) * Hc;
  const u64 *hp = (const u64 *)(hb + ro) + (lane >> 4) * 2;
  const u64 *rp = (const u64 *)(rb + ro) + (lane >> 4) * 2;
  for (int ks = 0; ks < NK; ks += KB) {
    u64 hv[2 * KB], rv[2 * KB];
#pragma unroll
    for (int q = 0; q < KB; ++q) {
      hv[2 * q]     = ald64(hp + (size_t)(ks + q) * 8);
      hv[2 * q + 1] = ald64(hp + (size_t)(ks + q) * 8 + 1);
      rv[2 * q]     = ald64(rp + (size_t)(ks + q) * 8);
      rv[2 * q + 1] = ald64(rp + (size_t)(ks + q) * 8 + 1);
    }
#pragma unroll
    for (int q = 0; q < KB; ++q) {
      bfrag av;
#pragma unroll
      for (int w = 0; w < 2; ++w) {
        u64 hu = hv[2 * q + w], ru = rv[2 * q + w];
#pragma unroll
        for (int e = 0; e < 4; ++e) {
          float hf = b2f((unsigned short)(hu >> (16 * e)));
          float rf = b2f((unsigned short)(ru >> (16 * e)));
          av[w * 4 + e] = (short)f2b(hf * rf);
        }
      }
      const short *wp = wl + (((size_t)(nkoff + ks + q) * 2) * 64 + lane) * 8;
      acc[0] = __builtin_amdgcn_mfma_f32_16x16x32_bf16(av, *(const bfrag *)wp, acc[0], 0, 0, 0);
      acc[1] = __builtin_amdgcn_mfma_f32_16x16x32_bf16(av, *(const bfrag *)(wp + 512), acc[1], 0, 0, 0);
    }
  }
}

// x is a read-only input -> plain cached loads, convert fp32->bf16 in-reg.
__device__ void seg_x(f32x4 *acc, const float *xt, const short *wl,
                      int lane, int rbase) {
  const float4 *xp = (const float4 *)(xt + (size_t)(rbase + (lane & 15)) * Sc * Ic) + (lane >> 4) * 2;
  float4 xv[16];
#pragma unroll
  for (int q = 0; q < 8; ++q) {
    xv[2 * q]     = xp[(size_t)q * 8];
    xv[2 * q + 1] = xp[(size_t)q * 8 + 1];
  }
#pragma unroll
  for (int q = 0; q < 8; ++q) {
    bfrag av;
    const float *f0 = (const float *)&xv[2 * q];
    const float *f1 = (const float *)&xv[2 * q + 1];
#pragma unroll
    for (int e = 0; e < 4; ++e) {
      av[e]     = (short)f2b(f0[e]);
      av[4 + e] = (short)f2b(f1[e]);
    }
    const short *wp = wl + (((size_t)q * 2) * 64 + lane) * 8;
    acc[0] = __builtin_amdgcn_mfma_f32_16x16x32_bf16(av, *(const bfrag *)wp, acc[0], 0, 0, 0);
    acc[1] = __builtin_amdgcn_mfma_f32_16x16x32_bf16(av, *(const bfrag *)(wp + 512), acc[1], 0, 0, 0);
  }
}

// ---------------- epilogues -------------------------------------------------
// C layout: row = rbase + (lane>>4)*4 + j, col = c0 + nt*16 + (lane&15).
__device__ void store_sig(unsigned short *out, f32x4 *acc, int c0, int lane, int rbase) {
#pragma unroll
  for (int nt = 0; nt < 2; ++nt) {
    int col = c0 + nt * 16 + (lane & 15);
#pragma unroll
    for (int j = 0; j < 4; ++j) {
      float v = 1.f / (1.f + expf(-acc[nt][j]));
      float vo = __shfl_xor(v, 1);
      if (!(lane & 1)) {
        unsigned pk = (unsigned)f2b(v) | ((unsigned)f2b(vo) << 16);
        int row = rbase + (lane >> 4) * 4 + j;
        ast32((unsigned *)out + ((size_t)row * Hc + col) / 2, pk);
      }
    }
  }
}

__device__ void store_gupd(unsigned short *hnew, const unsigned short *hold,
                           const unsigned short *zb, f32x4 *acc, int c0, int lane, int rbase) {
#pragma unroll
  for (int nt = 0; nt < 2; ++nt) {
    int col = c0 + nt * 16 + (lane & 15);
#pragma unroll
    for (int j = 0; j < 4; ++j) {
      int row = rbase + (lane >> 4) * 4 + j;
      size_t idx = (size_t)row * Hc + col;
      float g = tanhf(acc[nt][j]);
      unsigned wz = ald32((const unsigned *)zb + idx / 2);
      unsigned wh = ald32((const unsigned *)hold + idx / 2);
      float zv = b2f((unsigned short)((col & 1) ? (wz >> 16) : (wz & 0xffff)));
      float hv = b2f((unsigned short)((col & 1) ? (wh >> 16) : (wh & 0xffff)));
      float hn = zv * hv + (1.f - zv) * g;
      float ho = __shfl_xor(hn, 1);
      if (!(lane & 1)) {
        unsigned pk = (unsigned)f2b(hn) | ((unsigned)f2b(ho) << 16);
        ast32((unsigned *)hnew + idx / 2, pk);
      }
    }
  }
}

// ---------------- gates -----------------------------------------------------
__device__ void gate_zr0(const Args &a, const short *wl, const float *bias, int c0, int t,
                         const unsigned short *h0c, unsigned short *out, int lane, int wid) {
  int rbase = wid * 16;
  float b0 = bias[c0 + (lane & 15)], b1 = bias[c0 + 16 + (lane & 15)];
  f32x4 acc[2] = {{b0, b0, b0, b0}, {b1, b1, b1, b1}};
  seg_x(acc, a.x + (size_t)t * Ic, wl, lane, rbase);
  seg_h(acc, h0c, wl, 8, 32, lane, rbase);
  store_sig(out, acc, c0, lane, rbase);
}

__device__ void gate_g0(const Args &a, const short *wl, const float *bias, int c0, int t,
                        const unsigned short *h0c, unsigned short *h0n, int lane, int wid) {
  int rbase = wid * 16;
  float b0 = bias[c0 + (lane & 15)], b1 = bias[c0 + 16 + (lane & 15)];
  f32x4 acc[2] = {{b0, b0, b0, b0}, {b1, b1, b1, b1}};
  seg_x(acc, a.x + (size_t)t * Ic, wl, lane, rbase);
  seg_rh(acc, h0c, a.r0, wl, 8, 32, lane, rbase);
  store_gupd(h0n, h0c, a.z0, acc, c0, lane, rbase);
}

__device__ void gate_zr1(const Args &a, const short *wl, const float *bias, int c0,
                         const unsigned short *h0n, const unsigned short *h1c,
                         unsigned short *out, int lane, int wid) {
  int rbase = wid * 16;
  float b0 = bias[c0 + (lane & 15)], b1 = bias[c0 + 16 + (lane & 15)];
  f32x4 acc[2] = {{b0, b0, b0, b0}, {b1, b1, b1, b1}};
  seg_h(acc, h0n, wl, 0, 32, lane, rbase);
  seg_h(acc, h1c, wl, 32, 32, lane, rbase);
  store_sig(out, acc, c0, lane, rbase);
}

__device__ void gate_g1(const Args &a, const short *wl, const float *bias, int c0,
                        const unsigned short *h0n, const unsigned short *h1c,
                        unsigned short *h1n, int lane, int wid) {
  int rbase = wid * 16;
  float b0 = bias[c0 + (lane & 15)], b1 = bias[c0 + 16 + (lane & 15)];
  f32x4 acc[2] = {{b0, b0, b0, b0}, {b1, b1, b1, b1}};
  seg_h(acc, h0n, wl, 0, 32, lane, rbase);
  seg_rh(acc, h1c, a.r1, wl, 32, 32, lane, rbase);
  store_gupd(h1n, h1c, a.z1, acc, c0, lane, rbase);
}

__device__ void gate_y(const Args &a, const short *wl, int c0, int tprev,
                       const unsigned short *h1, int lane, int wid) {
  int rbase = wid * 16;
  float b0 = a.bias[6][c0 + (lane & 15)], b1 = a.bias[6][c0 + 16 + (lane & 15)];
  f32x4 acc[2] = {{b0, b0, b0, b0}, {b1, b1, b1, b1}};
  seg_h(acc, h1, wl, 0, 32, lane, rbase);
#pragma unroll
  for (int nt = 0; nt < 2; ++nt) {
    int col = c0 + nt * 16 + (lane & 15);
#pragma unroll
    for (int j = 0; j < 4; ++j) {
      int row = rbase + (lane >> 4) * 4 + j;
      a.y[((size_t)row * Sc + tprev) * Oc + col] = acc[nt][j];
    }
  }
}

// ---------------- weight packing (once, into LDS) ---------------------------
__device__ void pack_weights(short *wl, const float *W1, int K1, int ld1,
                             const float *W2, int K2, int ld2, int c0) {
  int NK = (K1 + K2) / 32;
  for (int slot = threadIdx.x; slot < NK * 128; slot += TPB) {
    int ks = slot >> 7, rem = slot & 127, nt = rem >> 6, ln = rem & 63;
    int c = c0 + nt * 16 + (ln & 15);
    int k0 = ks * 32 + (ln >> 4) * 8;
    short *dst = wl + (((size_t)ks * 2 + nt) * 64 + ln) * 8;
#pragma unroll
    for (int j = 0; j < 8; ++j) {
      int k = k0 + j;
      float w = (k < K1) ? W1[(size_t)k * ld1 + c] : W2[(size_t)(k - K1) * ld2 + c];
      dst[j] = (short)f2b(w);
    }
  }
}

// ---------------- main ------------------------------------------------------
__global__ void __launch_bounds__(TPB) gru_mfma(Args a) {
  extern __shared__ short wl[];
  const int wg = blockIdx.x, tid = threadIdx.x;
  const int lane = tid & 63, wid = tid >> 6;
  const int role = (wg < 32) ? 0 : (wg < 64) ? 1 : (wg < 96) ? 2 :
                   (wg < 128) ? 3 : (wg < 160) ? 4 : (wg < 192) ? 5 : 6;
  const int c0 = (wg - role * 32) * 32;
  static const int K1tab[7] = {256, 256, 256, 1024, 1024, 1024, 1024};
  static const int K2tab[7] = {1024, 1024, 1024, 1024, 1024, 1024, 0};
  const int ld1 = (role == 6) ? Oc : Hc;

  pack_weights(wl, a.W1[role], K1tab[role], ld1, a.W2[role], K2tab[role], Hc, c0);

  // h state init (bf16, packed-pair agent stores)
  for (int u = wg * TPB + tid; u < Bc * Hc / 2; u += NWG * TPB) {
    int b = u >> 9, hp = (u & 511) * 2;
    const float *s0 = a.h0in + (size_t)(b * 2) * Hc + hp;
    const float *s1 = a.h0in + (size_t)(b * 2 + 1) * Hc + hp;
    ast32((unsigned *)a.h0a + u, (unsigned)f2b(s0[0]) | ((unsigned)f2b(s0[1]) << 16));
    ast32((unsigned *)a.h1a + u, (unsigned)f2b(s1[0]) | ((unsigned)f2b(s1[1]) << 16));
  }
  unsigned rnd = 0;
  gbar(a.bar, ++rnd, wg);

  // prime z0(0), r0(0)
  if (role == 0)      gate_zr0(a, wl, a.bias[0], c0, 0, a.h0a, a.z0, lane, wid);
  else if (role == 1) gate_zr0(a, wl, a.bias[1], c0, 0, a.h0a, a.r0, lane, wid);
  gbar(a.bar, ++rnd, wg);

  unsigned short *h0buf[2] = {a.h0a, a.h0b};
  unsigned short *h1buf[2] = {a.h1a, a.h1b};

  for (int t = 0; t < Sc; ++t) {
    const int cur = t & 1;
    const unsigned short *h0c = h0buf[cur], *h1c = h1buf[cur];
    unsigned short *h0n = h0buf[cur ^ 1], *h1n = h1buf[cur ^ 1];

    // PA: g0 + h0 update; y(t-1)
    if (role == 2)              gate_g0(a, wl, a.bias[2], c0, t, h0c, h0n, lane, wid);
    else if (role == 6 && t)    gate_y(a, wl, c0, t - 1, h1c, lane, wid);
    gbar(a.bar, ++rnd, wg);

    // PB: z1, r1; z0, r0 for t+1
    if (role == 3)                   gate_zr1(a, wl, a.bias[3], c0, h0n, h1c, a.z1, lane, wid);
    else if (role == 4)              gate_zr1(a, wl, a.bias[4], c0, h0n, h1c, a.r1, lane, wid);
    else if (role == 0 && t + 1 < Sc) gate_zr0(a, wl, a.bias[0], c0, t + 1, h0n, a.z0, lane, wid);
    else if (role == 1 && t + 1 < Sc) gate_zr0(a, wl, a.bias[1], c0, t + 1, h0n, a.r0, lane, wid);
    gbar(a.bar, ++rnd, wg);

    // PC: g1 + h1 update
    if (role == 5) gate_g1(a, wl, a.bias[5], c0, h0n, h1c, h1n, lane, wid);
    gbar(a.bar, ++rnd, wg);
  }

  // epilogue (after final barrier): y(1023) from h1 final (slot 0); hs fp32.
  if (role == 6) gate_y(a, wl, c0, Sc - 1, a.h1a, lane, wid);
  else if (role == 2) {
    for (int k = (wg - 64) * TPB + tid; k < Bc * 2 * Hc; k += 32 * TPB) {
      int b = k >> 11, l = (k >> 10) & 1, h = k & 1023;
      const unsigned short *src = l ? a.h1a : a.h0a;
      size_t idx = (size_t)b * Hc + h;
      unsigned wv = ald32((const unsigned *)src + idx / 2);
      a.hs[k] = b2f((unsigned short)((h & 1) ? (wv >> 16) : (wv & 0xffff)));
    }
  }
}

extern "C" void kernel_launch(void *const *d_in, const int *in_sizes, int n_in,
                              void *d_out, int out_size, void *d_ws, size_t ws_size,
                              hipStream_t stream) {
  (void)in_sizes; (void)n_in; (void)out_size; (void)ws_size;
  Args a;
  a.x    = (const float *)d_in[0];
  a.h0in = (const float *)d_in[1];
  // roles: 0=z0 1=r0 2=g0 3=z1 4=r1 5=g1 6=y
  a.W1[0] = (const float *)d_in[2];  a.W2[0] = (const float *)d_in[5];  a.bias[0] = (const float *)d_in[6];
  a.W1[1] = (const float *)d_in[3];  a.W2[1] = (const float *)d_in[7];  a.bias[1] = (const float *)d_in[8];
  a.W1[2] = (const float *)d_in[4];  a.W2[2] = (const float *)d_in[9];  a.bias[2] = (const float *)d_in[10];
  a.W1[3] = (const float *)d_in[11]; a.W2[3] = (const float *)d_in[14]; a.bias[3] = (const float *)d_in[15];
  a.W1[4] = (const float *)d_in[12]; a.W2[4] = (const float *)d_in[16]; a.bias[4] = (const float *)d_in[17];
  a.W1[5] = (const float *)d_in[13]; a.W2[5] = (const float *)d_in[18]; a.bias[5] = (const float *)d_in[19];
  a.W1[6] = (const float *)d_in[20]; a.W2[6] = nullptr;                 a.bias[6] = (const float *)d_in[21];

  char *w = (char *)d_ws;
  a.h0a = (unsigned short *)(w + 0);
  a.h0b = (unsigned short *)(w + 131072);
  a.h1a = (unsigned short *)(w + 262144);
  a.h1b = (unsigned short *)(w + 393216);
  a.z0  = (unsigned short *)(w + 524288);
  a.r0  = (unsigned short *)(w + 655360);
  a.z1  = (unsigned short *)(w + 786432);
  a.r1  = (unsigned short *)(w + 917504);
  a.bar = (unsigned *)(w + 1048576);
  a.y   = (float *)d_out;
  a.hs  = a.y + (size_t)Bc * Sc * Oc;

  hipMemsetAsync(a.bar, 0, 4096, stream);
  hipFuncSetAttribute((const void *)gru_mfma,
                      hipFuncAttributeMaxDynamicSharedMemorySize, 131072);
  gru_mfma<<<NWG, TPB, 131072, stream>>>(a);
}

// Round 9
// 66955.634 us; speedup vs baseline: 9.1828x; 1.1424x over previous
//
#include <hip/hip_runtime.h>
#include <hip/hip_bf16.h>
#include <stdint.h>

// ============================================================================
// 2-layer GRU — ROUND 9: store-based dataflow sync (no RMW barrier).
//   B=64, S=1024, I=256, H=1024, O=256, L=2
// R8 post-mortem: 3 RMW-tree barriers/step ~= 50+ serialized LLC RMWs each
// dominated 71us/step. This round: per-group "stamp" slots (plain release
// stores after syncthreads vmcnt-drain); consumers wave-poll producer groups.
// Stamp groups: zr0{z0,r0} g0 zr1{z1,r1} g1 y. stamp value t+2 == "step t done"
// (1 == init done). 2-stage pipeline; y off critical path; r*h fused at the
// r-producer (rh buffers) so g-gates are single-stream.
// Dependency thresholds (stamp units), WAR-audited:
//   zr0(t): g0>=t+1              g0(t): zr0>=t+2, g0>=t+1, zr1>=t+1, g1>=t+1
//   zr1(t): g0>=t+2, g1>=t+1     g1(t): zr1>=t+2, g1>=t+1, y>=t+1
//   y(t):   g1>=t+2              hs:    g0>=1025, g1>=1025
// ============================================================================

#define NWG 200
#define TPB 256

typedef unsigned long long u64;
typedef __attribute__((ext_vector_type(8))) short bfrag;
typedef __attribute__((ext_vector_type(4))) float f32x4;

constexpr int Bc = 64, Sc = 1024, Ic = 256, Hc = 1024, Oc = 256;

struct Args {
  const float *x, *h0in;
  const float *W1[7], *W2[7], *bias[7];
  unsigned short *h0a, *h0b, *h1a, *h1b, *z0, *rh0, *z1, *rh1;
  unsigned *sl;       // 200 stamp slots
  float *y, *hs;
};

__device__ __forceinline__ u64 ald64(const void *p) {
  return __hip_atomic_load((const u64 *)p, __ATOMIC_RELAXED, __HIP_MEMORY_SCOPE_AGENT);
}
__device__ __forceinline__ unsigned ald32(const void *p) {
  return __hip_atomic_load((const unsigned *)p, __ATOMIC_RELAXED, __HIP_MEMORY_SCOPE_AGENT);
}
__device__ __forceinline__ void ast32(void *p, unsigned v) {
  __hip_atomic_store((unsigned *)p, v, __ATOMIC_RELAXED, __HIP_MEMORY_SCOPE_AGENT);
}
__device__ __forceinline__ unsigned short f2b(float x) {
  __hip_bfloat16 b = __float2bfloat16(x);
  return __builtin_bit_cast(unsigned short, b);
}
__device__ __forceinline__ float b2f(unsigned short u) {
  return __uint_as_float(((unsigned)u) << 16);
}

// ---------------- dataflow sync --------------------------------------------
// Thread tid polls slot tid (tid<200). Group of slot: 0:[0,64) 1:[64,96)
// 2:[96,160) 3:[160,192) 4:[192,200). Wait until slot >= thr[group].
__device__ void wait_thr(const unsigned *sl, int t0, int t1, int t2, int t3, int t4) {
  __shared__ int notdone;
  const int tid = threadIdx.x;
  int need = 0;
  if (tid < 200) {
    int g = (tid < 64) ? 0 : (tid < 96) ? 1 : (tid < 160) ? 2 : (tid < 192) ? 3 : 4;
    need = (g == 0) ? t0 : (g == 1) ? t1 : (g == 2) ? t2 : (g == 3) ? t3 : t4;
  }
  while (true) {
    int ok = 1;
    if (need > 0)
      ok = ((int)ald32(sl + tid) >= need);
    if (tid == 0) notdone = 0;
    __syncthreads();
    if (!ok) notdone = 1;
    __syncthreads();
    if (!notdone) break;
    __builtin_amdgcn_s_sleep(8);
  }
}

__device__ void stamp(unsigned *sl, int wg, unsigned v) {
  __syncthreads();   // compiler emits vmcnt(0) drain before s_barrier: stores visible
  if (threadIdx.x == 0)
    __hip_atomic_store(sl + wg, v, __ATOMIC_RELEASE, __HIP_MEMORY_SCOPE_AGENT);
}

// ---------------- MFMA segments --------------------------------------------
// A-frag: lane holds A[rbase+(lane&15)][k0+(lane>>4)*8+j]. B in LDS at
// ((ks*2+nt)*64+lane)*8 shorts. All h-type segments have K=1024 (NK=32).
__device__ __forceinline__ void ldb(u64 *dst, const u64 *ap, int ks) {
#pragma unroll
  for (int q = 0; q < 8; ++q) {
    dst[2 * q]     = ald64(ap + (size_t)(ks + q) * 8);
    dst[2 * q + 1] = ald64(ap + (size_t)(ks + q) * 8 + 1);
  }
}
__device__ __forceinline__ void useb(f32x4 *acc, const u64 *src, const short *wl,
                                     int nkoff, int ks, int lane) {
#pragma unroll
  for (int q = 0; q < 8; ++q) {
    union { u64 u[2]; bfrag v; } cc;
    cc.u[0] = src[2 * q]; cc.u[1] = src[2 * q + 1];
    const short *wp = wl + (((size_t)(nkoff + ks + q) * 2) * 64 + lane) * 8;
    acc[0] = __builtin_amdgcn_mfma_f32_16x16x32_bf16(cc.v, *(const bfrag *)wp, acc[0], 0, 0, 0);
    acc[1] = __builtin_amdgcn_mfma_f32_16x16x32_bf16(cc.v, *(const bfrag *)(wp + 512), acc[1], 0, 0, 0);
  }
}
// software-pipelined K=1024 segment (4 batches, 2-deep)
__device__ void seg_h(f32x4 *acc, const unsigned short *hb, const short *wl,
                      int nkoff, int lane, int rbase) {
  const u64 *ap = (const u64 *)(hb + (size_t)(rbase + (lane & 15)) * Hc) + (lane >> 4) * 2;
  u64 A[16], B[16];
  ldb(A, ap, 0);
  ldb(B, ap, 8);
  useb(acc, A, wl, nkoff, 0, lane);
  ldb(A, ap, 16);
  useb(acc, B, wl, nkoff, 8, lane);
  ldb(B, ap, 24);
  useb(acc, A, wl, nkoff, 16, lane);
  useb(acc, B, wl, nkoff, 24, lane);
}
// x segment: K=256 (slices 0-7), fp32 input, cached loads, cvt in-reg
__device__ void seg_x(f32x4 *acc, const float *xt, const short *wl, int lane, int rbase) {
  const float4 *xp = (const float4 *)(xt + (size_t)(rbase + (lane & 15)) * Sc * Ic) + (lane >> 4) * 2;
  float4 xv[16];
#pragma unroll
  for (int q = 0; q < 8; ++q) {
    xv[2 * q]     = xp[(size_t)q * 8];
    xv[2 * q + 1] = xp[(size_t)q * 8 + 1];
  }
#pragma unroll
  for (int q = 0; q < 8; ++q) {
    bfrag av;
    const float *f0 = (const float *)&xv[2 * q];
    const float *f1 = (const float *)&xv[2 * q + 1];
#pragma unroll
    for (int e = 0; e < 4; ++e) {
      av[e]     = (short)f2b(f0[e]);
      av[4 + e] = (short)f2b(f1[e]);
    }
    const short *wp = wl + (((size_t)q * 2) * 64 + lane) * 8;
    acc[0] = __builtin_amdgcn_mfma_f32_16x16x32_bf16(av, *(const bfrag *)wp, acc[0], 0, 0, 0);
    acc[1] = __builtin_amdgcn_mfma_f32_16x16x32_bf16(av, *(const bfrag *)(wp + 512), acc[1], 0, 0, 0);
  }
}

// ---------------- epilogues (preloaded, batched) ----------------------------
// C layout: row = rbase+(lane>>4)*4+j, col = c0+nt*16+(lane&15).
__device__ void store_sig(unsigned short *out, f32x4 *acc, int c0, int lane, int rbase) {
#pragma unroll
  for (int nt = 0; nt < 2; ++nt) {
    int col = c0 + nt * 16 + (lane & 15);
#pragma unroll
    for (int j = 0; j < 4; ++j) {
      float v = 1.f / (1.f + expf(-acc[nt][j]));
      float vo = __shfl_xor(v, 1);
      if (!(lane & 1)) {
        int row = rbase + (lane >> 4) * 4 + j;
        ast32((unsigned *)out + (((size_t)row * Hc + col) >> 1),
              (unsigned)f2b(v) | ((unsigned)f2b(vo) << 16));
      }
    }
  }
}
// r-gate: write rh = sigmoid(acc) * h elementwise (rounding identical to R8)
__device__ void store_rh(unsigned short *out, const unsigned short *hb, f32x4 *acc,
                         int c0, int lane, int rbase) {
  unsigned hw[8];
#pragma unroll
  for (int nt = 0; nt < 2; ++nt)
#pragma unroll
    for (int j = 0; j < 4; ++j)
      if (!(lane & 1)) {
        int col = c0 + nt * 16 + (lane & 15);
        int row = rbase + (lane >> 4) * 4 + j;
        hw[nt * 4 + j] = ald32((const unsigned *)hb + (((size_t)row * Hc + col) >> 1));
      }
#pragma unroll
  for (int nt = 0; nt < 2; ++nt) {
    int col = c0 + nt * 16 + (lane & 15);
#pragma unroll
    for (int j = 0; j < 4; ++j) {
      float v = 1.f / (1.f + expf(-acc[nt][j]));
      float vo = __shfl_xor(v, 1);
      if (!(lane & 1)) {
        unsigned w = hw[nt * 4 + j];
        int row = rbase + (lane >> 4) * 4 + j;
        unsigned pk = (unsigned)f2b(v * b2f((unsigned short)(w & 0xffff)))
                    | ((unsigned)f2b(vo * b2f((unsigned short)(w >> 16))) << 16);
        ast32((unsigned *)out + (((size_t)row * Hc + col) >> 1), pk);
      }
    }
  }
}
__device__ void store_gupd(unsigned short *hnew, const unsigned short *hold,
                           const unsigned short *zb, f32x4 *acc, int c0, int lane, int rbase) {
  unsigned zw[8], hw[8];
#pragma unroll
  for (int nt = 0; nt < 2; ++nt)
#pragma unroll
    for (int j = 0; j < 4; ++j)
      if (!(lane & 1)) {
        int col = c0 + nt * 16 + (lane & 15);
        size_t iw = ((size_t)(rbase + (lane >> 4) * 4 + j) * Hc + col) >> 1;
        zw[nt * 4 + j] = ald32((const unsigned *)zb + iw);
        hw[nt * 4 + j] = ald32((const unsigned *)hold + iw);
      }
#pragma unroll
  for (int nt = 0; nt < 2; ++nt) {
    int col = c0 + nt * 16 + (lane & 15);
#pragma unroll
    for (int j = 0; j < 4; ++j) {
      float g = tanhf(acc[nt][j]);
      float go = __shfl_xor(g, 1);
      if (!(lane & 1)) {
        unsigned wz = zw[nt * 4 + j], wh = hw[nt * 4 + j];
        float zl = b2f((unsigned short)(wz & 0xffff)), zh = b2f((unsigned short)(wz >> 16));
        float hl = b2f((unsigned short)(wh & 0xffff)), hh = b2f((unsigned short)(wh >> 16));
        float hn0 = zl * hl + (1.f - zl) * g;
        float hn1 = zh * hh + (1.f - zh) * go;
        size_t iw = ((size_t)(rbase + (lane >> 4) * 4 + j) * Hc + col) >> 1;
        ast32((unsigned *)hnew + iw, (unsigned)f2b(hn0) | ((unsigned)f2b(hn1) << 16));
      }
    }
  }
}

// ---------------- weight packing (once, into LDS) ---------------------------
__device__ void pack_weights(short *wl, const float *W1, int K1, int ld1,
                             const float *W2, int K2, int ld2, int c0) {
  int NK = (K1 + K2) / 32;
  for (int slot = threadIdx.x; slot < NK * 128; slot += TPB) {
    int ks = slot >> 7, rem = slot & 127, nt = rem >> 6, ln = rem & 63;
    int c = c0 + nt * 16 + (ln & 15);
    int k0 = ks * 32 + (ln >> 4) * 8;
    short *dst = wl + (((size_t)ks * 2 + nt) * 64 + ln) * 8;
#pragma unroll
    for (int j = 0; j < 8; ++j) {
      int k = k0 + j;
      float w = (k < K1) ? W1[(size_t)k * ld1 + c] : W2[(size_t)(k - K1) * ld2 + c];
      dst[j] = (short)f2b(w);
    }
  }
}

// ---------------- main ------------------------------------------------------
__global__ void __launch_bounds__(TPB) gru_df(Args a) {
  extern __shared__ short wl[];
  const int wg = blockIdx.x, tid = threadIdx.x;
  const int lane = tid & 63, wid = tid >> 6, rbase = wid * 16;
  // gate id: 0=z0 1=r0 2=g0 3=z1 4=r1 5=g1 6=y
  const int gate = (wg < 32) ? 0 : (wg < 64) ? 1 : (wg < 96) ? 2 :
                   (wg < 128) ? 3 : (wg < 160) ? 4 : (wg < 192) ? 5 : 6;
  const int c0 = (gate == 6) ? (wg - 192) * 32 : (wg - gate * 32) * 32;
  static const int K1tab[7] = {256, 256, 256, 1024, 1024, 1024, 1024};
  static const int K2tab[7] = {1024, 1024, 1024, 1024, 1024, 1024, 0};
  const int ld1 = (gate == 6) ? Oc : Hc;

  pack_weights(wl, a.W1[gate], K1tab[gate], ld1, a.W2[gate], K2tab[gate], Hc, c0);

  // init h(-1) into the "odd" buffers (h0b/h1b), packed bf16
  for (int u = wg * TPB + tid; u < Bc * Hc / 2; u += NWG * TPB) {
    int b = u >> 9, hp = (u & 511) * 2;
    const float *s0 = a.h0in + (size_t)(b * 2) * Hc + hp;
    const float *s1 = a.h0in + (size_t)(b * 2 + 1) * Hc + hp;
    ast32((unsigned *)a.h0b + u, (unsigned)f2b(s0[0]) | ((unsigned)f2b(s0[1]) << 16));
    ast32((unsigned *)a.h1b + u, (unsigned)f2b(s1[0]) | ((unsigned)f2b(s1[1]) << 16));
  }
  stamp(a.sl, wg, 1);
  wait_thr(a.sl, 1, 1, 1, 1, 1);

  const float *bias = a.bias[gate];

  if (gate <= 1) {                                   // ---- zr0 group
    for (int t = 0; t < Sc; ++t) {
      wait_thr(a.sl, 0, t + 1, 0, 0, 0);
      const unsigned short *h0c = (t & 1) ? a.h0a : a.h0b;     // h0(t-1)
      float b0 = bias[c0 + (lane & 15)], b1 = bias[c0 + 16 + (lane & 15)];
      f32x4 acc[2] = {{b0, b0, b0, b0}, {b1, b1, b1, b1}};
      seg_x(acc, a.x + (size_t)t * Ic, wl, lane, rbase);
      seg_h(acc, h0c, wl, 8, lane, rbase);
      if (gate == 0) store_sig(a.z0, acc, c0, lane, rbase);
      else           store_rh(a.rh0, h0c, acc, c0, lane, rbase);
      stamp(a.sl, wg, t + 2);
    }
  } else if (gate == 2) {                            // ---- g0 group
    for (int t = 0; t < Sc; ++t) {
      wait_thr(a.sl, t + 2, t + 1, t + 1, t + 1, 0);
      const unsigned short *h0c = (t & 1) ? a.h0a : a.h0b;
      unsigned short *h0n = (t & 1) ? a.h0b : a.h0a;           // h0(t)
      float b0 = bias[c0 + (lane & 15)], b1 = bias[c0 + 16 + (lane & 15)];
      f32x4 acc[2] = {{b0, b0, b0, b0}, {b1, b1, b1, b1}};
      seg_x(acc, a.x + (size_t)t * Ic, wl, lane, rbase);
      seg_h(acc, a.rh0, wl, 8, lane, rbase);
      store_gupd(h0n, h0c, a.z0, acc, c0, lane, rbase);
      stamp(a.sl, wg, t + 2);
    }
    // hs epilogue: final states h0(1023)=h0b, h1(1023)=h1b
    wait_thr(a.sl, 0, Sc + 1, 0, Sc + 1, 0);
    for (int k = (wg - 64) * TPB + tid; k < Bc * 2 * Hc; k += 32 * TPB) {
      int b = k >> 11, l = (k >> 10) & 1, h = k & 1023;
      const unsigned short *src = l ? a.h1b : a.h0b;
      size_t idx = (size_t)b * Hc + h;
      unsigned wv = ald32((const unsigned *)src + idx / 2);
      a.hs[k] = b2f((unsigned short)((h & 1) ? (wv >> 16) : (wv & 0xffff)));
    }
  } else if (gate <= 4) {                            // ---- zr1 group
    for (int t = 0; t < Sc; ++t) {
      wait_thr(a.sl, 0, t + 2, 0, t + 1, 0);
      const unsigned short *h0n = (t & 1) ? a.h0b : a.h0a;     // h0(t)
      const unsigned short *h1c = (t & 1) ? a.h1a : a.h1b;     // h1(t-1)
      float b0 = bias[c0 + (lane & 15)], b1 = bias[c0 + 16 + (lane & 15)];
      f32x4 acc[2] = {{b0, b0, b0, b0}, {b1, b1, b1, b1}};
      seg_h(acc, h0n, wl, 0, lane, rbase);
      seg_h(acc, h1c, wl, 32, lane, rbase);
      if (gate == 3) store_sig(a.z1, acc, c0, lane, rbase);
      else           store_rh(a.rh1, h1c, acc, c0, lane, rbase);
      stamp(a.sl, wg, t + 2);
    }
  } else if (gate == 5) {                            // ---- g1 group
    for (int t = 0; t < Sc; ++t) {
      wait_thr(a.sl, 0, 0, t + 2, t + 1, t + 1);
      const unsigned short *h0n = (t & 1) ? a.h0b : a.h0a;
      const unsigned short *h1c = (t & 1) ? a.h1a : a.h1b;
      unsigned short *h1n = (t & 1) ? a.h1b : a.h1a;           // h1(t)
      float b0 = bias[c0 + (lane & 15)], b1 = bias[c0 + 16 + (lane & 15)];
      f32x4 acc[2] = {{b0, b0, b0, b0}, {b1, b1, b1, b1}};
      seg_h(acc, h0n, wl, 0, lane, rbase);
      seg_h(acc, a.rh1, wl, 32, lane, rbase);
      store_gupd(h1n, h1c, a.z1, acc, c0, lane, rbase);
      stamp(a.sl, wg, t + 2);
    }
  } else {                                           // ---- y group
    for (int t = 0; t < Sc; ++t) {
      wait_thr(a.sl, 0, 0, 0, t + 2, 0);
      const unsigned short *h1t = (t & 1) ? a.h1b : a.h1a;     // h1(t)
      float b0 = bias[c0 + (lane & 15)], b1 = bias[c0 + 16 + (lane & 15)];
      f32x4 acc[2] = {{b0, b0, b0, b0}, {b1, b1, b1, b1}};
      seg_h(acc, h1t, wl, 0, lane, rbase);
#pragma unroll
      for (int nt = 0; nt < 2; ++nt) {
        int col = c0 + nt * 16 + (lane & 15);
#pragma unroll
        for (int j = 0; j < 4; ++j) {
          int row = rbase + (lane >> 4) * 4 + j;
          a.y[((size_t)row * Sc + t) * Oc + col] = acc[nt][j];
        }
      }
      stamp(a.sl, wg, t + 2);
    }
  }
}

extern "C" void kernel_launch(void *const *d_in, const int *in_sizes, int n_in,
                              void *d_out, int out_size, void *d_ws, size_t ws_size,
                              hipStream_t stream) {
  (void)in_sizes; (void)n_in; (void)out_size; (void)ws_size;
  Args a;
  a.x    = (const float *)d_in[0];
  a.h0in = (const float *)d_in[1];
  // gate ids: 0=z0 1=r0 2=g0 3=z1 4=r1 5=g1 6=y
  a.W1[0] = (const float *)d_in[2];  a.W2[0] = (const float *)d_in[5];  a.bias[0] = (const float *)d_in[6];
  a.W1[1] = (const float *)d_in[3];  a.W2[1] = (const float *)d_in[7];  a.bias[1] = (const float *)d_in[8];
  a.W1[2] = (const float *)d_in[4];  a.W2[2] = (const float *)d_in[9];  a.bias[2] = (const float *)d_in[10];
  a.W1[3] = (const float *)d_in[11]; a.W2[3] = (const float *)d_in[14]; a.bias[3] = (const float *)d_in[15];
  a.W1[4] = (const float *)d_in[12]; a.W2[4] = (const float *)d_in[16]; a.bias[4] = (const float *)d_in[17];
  a.W1[5] = (const float *)d_in[13]; a.W2[5] = (const float *)d_in[18]; a.bias[5] = (const float *)d_in[19];
  a.W1[6] = (const float *)d_in[20]; a.W2[6] = nullptr;                 a.bias[6] = (const float *)d_in[21];

  char *w = (char *)d_ws;
  a.h0a = (unsigned short *)(w + 0);
  a.h0b = (unsigned short *)(w + 131072);
  a.h1a = (unsigned short *)(w + 262144);
  a.h1b = (unsigned short *)(w + 393216);
  a.z0  = (unsigned short *)(w + 524288);
  a.rh0 = (unsigned short *)(w + 655360);
  a.z1  = (unsigned short *)(w + 786432);
  a.rh1 = (unsigned short *)(w + 917504);
  a.sl  = (unsigned *)(w + 1048576);
  a.y   = (float *)d_out;
  a.hs  = a.y + (size_t)Bc * Sc * Oc;

  hipMemsetAsync(a.sl, 0, 1024, stream);
  hipFuncSetAttribute((const void *)gru_df,
                      hipFuncAttributeMaxDynamicSharedMemorySize, 131072);
  gru_df<<<NWG, TPB, 131072, stream>>>(a);
}

// Round 10
// 47414.142 us; speedup vs baseline: 12.9674x; 1.4121x over previous
//
#include <hip/hip_runtime.h>
#include <hip/hip_bf16.h>
#include <stdint.h>

// ============================================================================
// 2-layer GRU — ROUND 10: contention-free dataflow sync.
//   B=64, S=1024, I=256, H=1024, O=256, L=2
// R9 post-mortem: polling ALL 200 packed stamp slots (13 cache lines) from
// all 200 WGs saturated those lines; stamp stores queued behind the read
// storm -> ~30us/hop. Fix: 128B-padded slots + poll ONLY needed slots
// (<=160 threads, 1 slot each) + z/rh double-buffered so WAR waits are
// subsumed. Pipeline/gates/numerics identical to R9.
// Stamp groups (slot = wg, padded x32 u32): zr0[0,64) g0[64,96) zr1[96,160)
// g1[160,192) y[192,200). stamp t+2 == step t done (1 == init done).
// Waits (stamp >= t+off):
//   zr0(t): g0 off1        g0(t): zr0 off2, zr1 off0, g1 off0
//   zr1(t): g0 off2, g1 off1    g1(t): zr1 off2, g0 off2, y off0
//   y(t):   g1 off2        hs:    g0,g1 >= Sc+1
// Buffers: h0(t) in h0buf[t&1]; h(-1) in buf1. z*/rh* in [t&1].
// ============================================================================

#define NWG 200
#define TPB 256

typedef unsigned long long u64;
typedef __attribute__((ext_vector_type(8))) short bfrag;
typedef __attribute__((ext_vector_type(4))) float f32x4;

constexpr int Bc = 64, Sc = 1024, Ic = 256, Hc = 1024, Oc = 256;

struct Args {
  const float *x, *h0in;
  const float *W1[7], *W2[7], *bias[7];
  unsigned short *h0[2], *h1[2], *z0[2], *rh0[2], *z1[2], *rh1[2];
  unsigned *sl;       // 200 stamp slots, 128B apart
  float *y, *hs;
};

__device__ __forceinline__ u64 ald64(const void *p) {
  return __hip_atomic_load((const u64 *)p, __ATOMIC_RELAXED, __HIP_MEMORY_SCOPE_AGENT);
}
__device__ __forceinline__ unsigned ald32(const void *p) {
  return __hip_atomic_load((const unsigned *)p, __ATOMIC_RELAXED, __HIP_MEMORY_SCOPE_AGENT);
}
__device__ __forceinline__ void ast32(void *p, unsigned v) {
  __hip_atomic_store((unsigned *)p, v, __ATOMIC_RELAXED, __HIP_MEMORY_SCOPE_AGENT);
}
__device__ __forceinline__ unsigned short f2b(float x) {
  __hip_bfloat16 b = __float2bfloat16(x);
  return __builtin_bit_cast(unsigned short, b);
}
__device__ __forceinline__ float b2f(unsigned short u) {
  return __uint_as_float(((unsigned)u) << 16);
}

// ---------------- dataflow sync --------------------------------------------
// Each thread owns at most one (slot, threshold). Poll until satisfied.
__device__ void waitslots(const unsigned *sl, int pslot, int pthr) {
  __shared__ int notdone;
  while (true) {
    int bad = 0;
    if (pslot >= 0)
      bad = ((int)ald32(sl + (size_t)pslot * 32) < pthr);
    if (threadIdx.x == 0) notdone = 0;
    __syncthreads();
    if (bad) notdone = 1;
    __syncthreads();
    if (!notdone) break;
    __builtin_amdgcn_s_sleep(2);
  }
}

__device__ void stamp(unsigned *sl, int wg, unsigned v) {
  __syncthreads();   // compiler drains vmcnt before s_barrier: stores visible
  if (threadIdx.x == 0)
    __hip_atomic_store(sl + (size_t)wg * 32, v, __ATOMIC_RELEASE, __HIP_MEMORY_SCOPE_AGENT);
}

// ---------------- MFMA segments --------------------------------------------
__device__ __forceinline__ void ldb(u64 *dst, const u64 *ap, int ks) {
#pragma unroll
  for (int q = 0; q < 8; ++q) {
    dst[2 * q]     = ald64(ap + (size_t)(ks + q) * 8);
    dst[2 * q + 1] = ald64(ap + (size_t)(ks + q) * 8 + 1);
  }
}
__device__ __forceinline__ void useb(f32x4 *acc, const u64 *src, const short *wl,
                                     int nkoff, int ks, int lane) {
#pragma unroll
  for (int q = 0; q < 8; ++q) {
    union { u64 u[2]; bfrag v; } cc;
    cc.u[0] = src[2 * q]; cc.u[1] = src[2 * q + 1];
    const short *wp = wl + (((size_t)(nkoff + ks + q) * 2) * 64 + lane) * 8;
    acc[0] = __builtin_amdgcn_mfma_f32_16x16x32_bf16(cc.v, *(const bfrag *)wp, acc[0], 0, 0, 0);
    acc[1] = __builtin_amdgcn_mfma_f32_16x16x32_bf16(cc.v, *(const bfrag *)(wp + 512), acc[1], 0, 0, 0);
  }
}
__device__ void seg_h(f32x4 *acc, const unsigned short *hb, const short *wl,
                      int nkoff, int lane, int rbase) {
  const u64 *ap = (const u64 *)(hb + (size_t)(rbase + (lane & 15)) * Hc) + (lane >> 4) * 2;
  u64 A[16], B[16];
  ldb(A, ap, 0);
  ldb(B, ap, 8);
  useb(acc, A, wl, nkoff, 0, lane);
  ldb(A, ap, 16);
  useb(acc, B, wl, nkoff, 8, lane);
  ldb(B, ap, 24);
  useb(acc, A, wl, nkoff, 16, lane);
  useb(acc, B, wl, nkoff, 24, lane);
}
__device__ void seg_x(f32x4 *acc, const float *xt, const short *wl, int lane, int rbase) {
  const float4 *xp = (const float4 *)(xt + (size_t)(rbase + (lane & 15)) * Sc * Ic) + (lane >> 4) * 2;
  float4 xv[16];
#pragma unroll
  for (int q = 0; q < 8; ++q) {
    xv[2 * q]     = xp[(size_t)q * 8];
    xv[2 * q + 1] = xp[(size_t)q * 8 + 1];
  }
#pragma unroll
  for (int q = 0; q < 8; ++q) {
    bfrag av;
    const float *f0 = (const float *)&xv[2 * q];
    const float *f1 = (const float *)&xv[2 * q + 1];
#pragma unroll
    for (int e = 0; e < 4; ++e) {
      av[e]     = (short)f2b(f0[e]);
      av[4 + e] = (short)f2b(f1[e]);
    }
    const short *wp = wl + (((size_t)q * 2) * 64 + lane) * 8;
    acc[0] = __builtin_amdgcn_mfma_f32_16x16x32_bf16(av, *(const bfrag *)wp, acc[0], 0, 0, 0);
    acc[1] = __builtin_amdgcn_mfma_f32_16x16x32_bf16(av, *(const bfrag *)(wp + 512), acc[1], 0, 0, 0);
  }
}

// ---------------- epilogues --------------------------------------------------
__device__ void store_sig(unsigned short *out, f32x4 *acc, int c0, int lane, int rbase) {
#pragma unroll
  for (int nt = 0; nt < 2; ++nt) {
    int col = c0 + nt * 16 + (lane & 15);
#pragma unroll
    for (int j = 0; j < 4; ++j) {
      float v = 1.f / (1.f + expf(-acc[nt][j]));
      float vo = __shfl_xor(v, 1);
      if (!(lane & 1)) {
        int row = rbase + (lane >> 4) * 4 + j;
        ast32((unsigned *)out + (((size_t)row * Hc + col) >> 1),
              (unsigned)f2b(v) | ((unsigned)f2b(vo) << 16));
      }
    }
  }
}
__device__ void store_rh(unsigned short *out, const unsigned short *hb, f32x4 *acc,
                         int c0, int lane, int rbase) {
  unsigned hw[8];
#pragma unroll
  for (int nt = 0; nt < 2; ++nt)
#pragma unroll
    for (int j = 0; j < 4; ++j)
      if (!(lane & 1)) {
        int col = c0 + nt * 16 + (lane & 15);
        int row = rbase + (lane >> 4) * 4 + j;
        hw[nt * 4 + j] = ald32((const unsigned *)hb + (((size_t)row * Hc + col) >> 1));
      }
#pragma unroll
  for (int nt = 0; nt < 2; ++nt) {
    int col = c0 + nt * 16 + (lane & 15);
#pragma unroll
    for (int j = 0; j < 4; ++j) {
      float v = 1.f / (1.f + expf(-acc[nt][j]));
      float vo = __shfl_xor(v, 1);
      if (!(lane & 1)) {
        unsigned w = hw[nt * 4 + j];
        int row = rbase + (lane >> 4) * 4 + j;
        unsigned pk = (unsigned)f2b(v * b2f((unsigned short)(w & 0xffff)))
                    | ((unsigned)f2b(vo * b2f((unsigned short)(w >> 16))) << 16);
        ast32((unsigned *)out + (((size_t)row * Hc + col) >> 1), pk);
      }
    }
  }
}
__device__ void store_gupd(unsigned short *hnew, const unsigned short *hold,
                           const unsigned short *zb, f32x4 *acc, int c0, int lane, int rbase) {
  unsigned zw[8], hw[8];
#pragma unroll
  for (int nt = 0; nt < 2; ++nt)
#pragma unroll
    for (int j = 0; j < 4; ++j)
      if (!(lane & 1)) {
        int col = c0 + nt * 16 + (lane & 15);
        size_t iw = ((size_t)(rbase + (lane >> 4) * 4 + j) * Hc + col) >> 1;
        zw[nt * 4 + j] = ald32((const unsigned *)zb + iw);
        hw[nt * 4 + j] = ald32((const unsigned *)hold + iw);
      }
#pragma unroll
  for (int nt = 0; nt < 2; ++nt) {
    int col = c0 + nt * 16 + (lane & 15);
#pragma unroll
    for (int j = 0; j < 4; ++j) {
      float g = tanhf(acc[nt][j]);
      float go = __shfl_xor(g, 1);
      if (!(lane & 1)) {
        unsigned wz = zw[nt * 4 + j], wh = hw[nt * 4 + j];
        float zl = b2f((unsigned short)(wz & 0xffff)), zh = b2f((unsigned short)(wz >> 16));
        float hl = b2f((unsigned short)(wh & 0xffff)), hh = b2f((unsigned short)(wh >> 16));
        float hn0 = zl * hl + (1.f - zl) * g;
        float hn1 = zh * hh + (1.f - zh) * go;
        size_t iw = ((size_t)(rbase + (lane >> 4) * 4 + j) * Hc + col) >> 1;
        ast32((unsigned *)hnew + iw, (unsigned)f2b(hn0) | ((unsigned)f2b(hn1) << 16));
      }
    }
  }
}

// ---------------- weight packing --------------------------------------------
__device__ void pack_weights(short *wl, const float *W1, int K1, int ld1,
                             const float *W2, int K2, int ld2, int c0) {
  int NK = (K1 + K2) / 32;
  for (int slot = threadIdx.x; slot < NK * 128; slot += TPB) {
    int ks = slot >> 7, rem = slot & 127, nt = rem >> 6, ln = rem & 63;
    int c = c0 + nt * 16 + (ln & 15);
    int k0 = ks * 32 + (ln >> 4) * 8;
    short *dst = wl + (((size_t)ks * 2 + nt) * 64 + ln) * 8;
#pragma unroll
    for (int j = 0; j < 8; ++j) {
      int k = k0 + j;
      float w = (k < K1) ? W1[(size_t)k * ld1 + c] : W2[(size_t)(k - K1) * ld2 + c];
      dst[j] = (short)f2b(w);
    }
  }
}

// ---------------- main ------------------------------------------------------
__global__ void __launch_bounds__(TPB) gru_df(Args a) {
  extern __shared__ short wl[];
  const int wg = blockIdx.x, tid = threadIdx.x;
  const int lane = tid & 63, wid = tid >> 6, rbase = wid * 16;
  const int gate = (wg < 32) ? 0 : (wg < 64) ? 1 : (wg < 96) ? 2 :
                   (wg < 128) ? 3 : (wg < 160) ? 4 : (wg < 192) ? 5 : 6;
  const int c0 = (gate == 6) ? (wg - 192) * 32 : (wg - gate * 32) * 32;
  static const int K1tab[7] = {256, 256, 256, 1024, 1024, 1024, 1024};
  static const int K2tab[7] = {1024, 1024, 1024, 1024, 1024, 1024, 0};
  const int ld1 = (gate == 6) ? Oc : Hc;

  pack_weights(wl, a.W1[gate], K1tab[gate], ld1, a.W2[gate], K2tab[gate], Hc, c0);

  // per-thread poll assignment: (slot, threshold offset); thr = t + off
  int pslot = -1, poff = 0;
  if (gate <= 1) {
    if (tid < 32) { pslot = 64 + tid; poff = 1; }                 // g0
  } else if (gate == 2) {
    if (tid < 64)       { pslot = tid;              poff = 2; }   // zr0
    else if (tid < 128) { pslot = 96 + (tid - 64);  poff = 0; }   // zr1 (WAR)
    else if (tid < 160) { pslot = 160 + (tid - 128); poff = 0; }  // g1 (WAR)
  } else if (gate <= 4) {
    if (tid < 32)      { pslot = 64 + tid;          poff = 2; }   // g0
    else if (tid < 64) { pslot = 160 + (tid - 32);  poff = 1; }   // g1
  } else if (gate == 5) {
    if (tid < 64)       { pslot = 96 + tid;         poff = 2; }   // zr1
    else if (tid < 96)  { pslot = 64 + (tid - 64);  poff = 2; }   // g0
    else if (tid < 104) { pslot = 192 + (tid - 96); poff = 0; }   // y (WAR)
  } else {
    if (tid < 32) { pslot = 160 + tid; poff = 2; }                // g1
  }

  // init h(-1) into buf1 (h0[1], h1[1]), packed bf16
  for (int u = wg * TPB + tid; u < Bc * Hc / 2; u += NWG * TPB) {
    int b = u >> 9, hp = (u & 511) * 2;
    const float *s0 = a.h0in + (size_t)(b * 2) * Hc + hp;
    const float *s1 = a.h0in + (size_t)(b * 2 + 1) * Hc + hp;
    ast32((unsigned *)a.h0[1] + u, (unsigned)f2b(s0[0]) | ((unsigned)f2b(s0[1]) << 16));
    ast32((unsigned *)a.h1[1] + u, (unsigned)f2b(s1[0]) | ((unsigned)f2b(s1[1]) << 16));
  }
  stamp(a.sl, wg, 1);
  waitslots(a.sl, (tid < NWG) ? tid : -1, 1);

  const float *bias = a.bias[gate];

  if (gate <= 1) {                                   // ---- zr0
    for (int t = 0; t < Sc; ++t) {
      waitslots(a.sl, pslot, (pslot >= 0) ? t + poff : 0);
      const unsigned short *h0c = a.h0[(t + 1) & 1];             // h0(t-1)
      float b0 = bias[c0 + (lane & 15)], b1 = bias[c0 + 16 + (lane & 15)];
      f32x4 acc[2] = {{b0, b0, b0, b0}, {b1, b1, b1, b1}};
      seg_x(acc, a.x + (size_t)t * Ic, wl, lane, rbase);
      seg_h(acc, h0c, wl, 8, lane, rbase);
      if (gate == 0) store_sig(a.z0[t & 1], acc, c0, lane, rbase);
      else           store_rh(a.rh0[t & 1], h0c, acc, c0, lane, rbase);
      stamp(a.sl, wg, t + 2);
    }
  } else if (gate == 2) {                            // ---- g0
    for (int t = 0; t < Sc; ++t) {
      waitslots(a.sl, pslot, (pslot >= 0) ? t + poff : 0);
      const unsigned short *h0c = a.h0[(t + 1) & 1];
      unsigned short *h0n = a.h0[t & 1];                          // h0(t)
      float b0 = bias[c0 + (lane & 15)], b1 = bias[c0 + 16 + (lane & 15)];
      f32x4 acc[2] = {{b0, b0, b0, b0}, {b1, b1, b1, b1}};
      seg_x(acc, a.x + (size_t)t * Ic, wl, lane, rbase);
      seg_h(acc, a.rh0[t & 1], wl, 8, lane, rbase);
      store_gupd(h0n, h0c, a.z0[t & 1], acc, c0, lane, rbase);
      stamp(a.sl, wg, t + 2);
    }
    // hs epilogue: final h0(1023), h1(1023) in buf[1023&1] = buf1
    {
      int eslot = -1;
      if (tid < 32) eslot = 64 + tid;
      else if (tid < 64) eslot = 160 + (tid - 32);
      waitslots(a.sl, eslot, Sc + 1);
    }
    for (int k = (wg - 64) * TPB + tid; k < Bc * 2 * Hc; k += 32 * TPB) {
      int b = k >> 11, l = (k >> 10) & 1, h = k & 1023;
      const unsigned short *src = l ? a.h1[1] : a.h0[1];
      size_t idx = (size_t)b * Hc + h;
      unsigned wv = ald32((const unsigned *)src + idx / 2);
      a.hs[k] = b2f((unsigned short)((h & 1) ? (wv >> 16) : (wv & 0xffff)));
    }
  } else if (gate <= 4) {                            // ---- zr1
    for (int t = 0; t < Sc; ++t) {
      waitslots(a.sl, pslot, (pslot >= 0) ? t + poff : 0);
      const unsigned short *h0n = a.h0[t & 1];                    // h0(t)
      const unsigned short *h1c = a.h1[(t + 1) & 1];              // h1(t-1)
      float b0 = bias[c0 + (lane & 15)], b1 = bias[c0 + 16 + (lane & 15)];
      f32x4 acc[2] = {{b0, b0, b0, b0}, {b1, b1, b1, b1}};
      seg_h(acc, h0n, wl, 0, lane, rbase);
      seg_h(acc, h1c, wl, 32, lane, rbase);
      if (gate == 3) store_sig(a.z1[t & 1], acc, c0, lane, rbase);
      else           store_rh(a.rh1[t & 1], h1c, acc, c0, lane, rbase);
      stamp(a.sl, wg, t + 2);
    }
  } else if (gate == 5) {                            // ---- g1
    for (int t = 0; t < Sc; ++t) {
      waitslots(a.sl, pslot, (pslot >= 0) ? t + poff : 0);
      const unsigned short *h0n = a.h0[t & 1];
      const unsigned short *h1c = a.h1[(t + 1) & 1];
      unsigned short *h1n = a.h1[t & 1];                          // h1(t)
      float b0 = bias[c0 + (lane & 15)], b1 = bias[c0 + 16 + (lane & 15)];
      f32x4 acc[2] = {{b0, b0, b0, b0}, {b1, b1, b1, b1}};
      seg_h(acc, h0n, wl, 0, lane, rbase);
      seg_h(acc, a.rh1[t & 1], wl, 32, lane, rbase);
      store_gupd(h1n, h1c, a.z1[t & 1], acc, c0, lane, rbase);
      stamp(a.sl, wg, t + 2);
    }
  } else {                                           // ---- y
    for (int t = 0; t < Sc; ++t) {
      waitslots(a.sl, pslot, (pslot >= 0) ? t + poff : 0);
      const unsigned short *h1t = a.h1[t & 1];                    // h1(t)
      float b0 = bias[c0 + (lane & 15)], b1 = bias[c0 + 16 + (lane & 15)];
      f32x4 acc[2] = {{b0, b0, b0, b0}, {b1, b1, b1, b1}};
      seg_h(acc, h1t, wl, 0, lane, rbase);
#pragma unroll
      for (int nt = 0; nt < 2; ++nt) {
        int col = c0 + nt * 16 + (lane & 15);
#pragma unroll
        for (int j = 0; j < 4; ++j) {
          int row = rbase + (lane >> 4) * 4 + j;
          a.y[((size_t)row * Sc + t) * Oc + col] = acc[nt][j];
        }
      }
      stamp(a.sl, wg, t + 2);
    }
  }
}

extern "C" void kernel_launch(void *const *d_in, const int *in_sizes, int n_in,
                              void *d_out, int out_size, void *d_ws, size_t ws_size,
                              hipStream_t stream) {
  (void)in_sizes; (void)n_in; (void)out_size; (void)ws_size;
  Args a;
  a.x    = (const float *)d_in[0];
  a.h0in = (const float *)d_in[1];
  a.W1[0] = (const float *)d_in[2];  a.W2[0] = (const float *)d_in[5];  a.bias[0] = (const float *)d_in[6];
  a.W1[1] = (const float *)d_in[3];  a.W2[1] = (const float *)d_in[7];  a.bias[1] = (const float *)d_in[8];
  a.W1[2] = (const float *)d_in[4];  a.W2[2] = (const float *)d_in[9];  a.bias[2] = (const float *)d_in[10];
  a.W1[3] = (const float *)d_in[11]; a.W2[3] = (const float *)d_in[14]; a.bias[3] = (const float *)d_in[15];
  a.W1[4] = (const float *)d_in[12]; a.W2[4] = (const float *)d_in[16]; a.bias[4] = (const float *)d_in[17];
  a.W1[5] = (const float *)d_in[13]; a.W2[5] = (const float *)d_in[18]; a.bias[5] = (const float *)d_in[19];
  a.W1[6] = (const float *)d_in[20]; a.W2[6] = nullptr;                 a.bias[6] = (const float *)d_in[21];

  char *w = (char *)d_ws;
  a.h0[0]  = (unsigned short *)(w + 0);
  a.h0[1]  = (unsigned short *)(w + 131072);
  a.h1[0]  = (unsigned short *)(w + 262144);
  a.h1[1]  = (unsigned short *)(w + 393216);
  a.z0[0]  = (unsigned short *)(w + 524288);
  a.z0[1]  = (unsigned short *)(w + 655360);
  a.rh0[0] = (unsigned short *)(w + 786432);
  a.rh0[1] = (unsigned short *)(w + 917504);
  a.z1[0]  = (unsigned short *)(w + 1048576);
  a.z1[1]  = (unsigned short *)(w + 1179648);
  a.rh1[0] = (unsigned short *)(w + 1310720);
  a.rh1[1] = (unsigned short *)(w + 1441792);
  a.sl     = (unsigned *)(w + 1572864);
  a.y   = (float *)d_out;
  a.hs  = a.y + (size_t)Bc * Sc * Oc;

  hipMemsetAsync(a.sl, 0, 32768, stream);
  hipFuncSetAttribute((const void *)gru_df,
                      hipFuncAttributeMaxDynamicSharedMemorySize, 131072);
  gru_df<<<NWG, TPB, 131072, stream>>>(a);
}

// Round 12
// 41912.076 us; speedup vs baseline: 14.6698x; 1.1313x over previous
//
#include <hip/hip_runtime.h>
#include <hip/hip_bf16.h>
#include <stdint.h>

// ============================================================================
// 2-layer GRU — ROUND 12: R11 (cached reads + LLC writes) with the fence
// intrinsic fixed: __builtin_amdgcn_fence(__ATOMIC_ACQUIRE, "agent").
//   B=64, S=1024, I=256, H=1024, O=256, L=2
// Theory (from R10 post-mortem): state reads were 8B sc1 atomics (bypass
// L1/L2) -> ~4.6M LLC transactions/step -> ~20us/hop. Fix: consumers poll
// stamp, then agent ACQUIRE fence (invalidates L1/L2), then PLAIN cached
// loads (16B A-frags): one LLC line-fill per 128B per XCD, shared via L2.
// Writes remain relaxed sc1 atomics; stamp is a release store after
// __syncthreads vmcnt-drain. Pipeline identical to R10.
// Stamp slots padded to 128B. stamp t+2 == step t done (1 == init done).
// Waits (stamp >= t+off):
//   zr0(t): g0 off1        g0(t): zr0 off2, zr1 off0, g1 off0
//   zr1(t): g0 off2, g1 off1    g1(t): zr1 off2, g0 off2, y off0
//   y(t):   g1 off2        hs:    g0,g1 >= Sc+1
// ============================================================================

#define NWG 200
#define TPB 256

typedef unsigned long long u64;
typedef __attribute__((ext_vector_type(8))) short bfrag;
typedef __attribute__((ext_vector_type(4))) float f32x4;

constexpr int Bc = 64, Sc = 1024, Ic = 256, Hc = 1024, Oc = 256;

struct Args {
  const float *x, *h0in;
  const float *W1[7], *W2[7], *bias[7];
  unsigned short *h0[2], *h1[2], *z0[2], *rh0[2], *z1[2], *rh1[2];
  unsigned *sl;       // 200 stamp slots, 128B apart
  float *y, *hs;
};

__device__ __forceinline__ unsigned ald32(const void *p) {
  return __hip_atomic_load((const unsigned *)p, __ATOMIC_RELAXED, __HIP_MEMORY_SCOPE_AGENT);
}
__device__ __forceinline__ void ast32(void *p, unsigned v) {
  __hip_atomic_store((unsigned *)p, v, __ATOMIC_RELAXED, __HIP_MEMORY_SCOPE_AGENT);
}
__device__ __forceinline__ unsigned short f2b(float x) {
  __hip_bfloat16 b = __float2bfloat16(x);
  return __builtin_bit_cast(unsigned short, b);
}
__device__ __forceinline__ float b2f(unsigned short u) {
  return __uint_as_float(((unsigned)u) << 16);
}

// ---------------- dataflow sync --------------------------------------------
// Each thread owns at most one (slot, threshold). After global success, an
// agent acquire fence invalidates L1/L2 so subsequent PLAIN loads are fresh.
__device__ void waitslots(const unsigned *sl, int pslot, int pthr) {
  __shared__ int notdone;
  while (true) {
    int bad = 0;
    if (pslot >= 0)
      bad = ((int)ald32(sl + (size_t)pslot * 32) < pthr);
    if (threadIdx.x == 0) notdone = 0;
    __syncthreads();
    if (bad) notdone = 1;
    __syncthreads();
    if (!notdone) break;
    __builtin_amdgcn_s_sleep(2);
  }
  __builtin_amdgcn_fence(__ATOMIC_ACQUIRE, "agent");
}

__device__ void stamp(unsigned *sl, int wg, unsigned v) {
  __syncthreads();   // drains vmcnt per wave: all sc1 stores at LLC
  if (threadIdx.x == 0)
    __hip_atomic_store(sl + (size_t)wg * 32, v, __ATOMIC_RELEASE, __HIP_MEMORY_SCOPE_AGENT);
}

// ---------------- MFMA segments (plain cached loads) ------------------------
__device__ __forceinline__ void use8(f32x4 *acc, const bfrag *A, const short *wl,
                                     int nkoff, int ks0, int lane) {
#pragma unroll
  for (int q = 0; q < 8; ++q) {
    const short *wp = wl + (((size_t)(nkoff + ks0 + q) * 2) * 64 + lane) * 8;
    acc[0] = __builtin_amdgcn_mfma_f32_16x16x32_bf16(A[q], *(const bfrag *)wp, acc[0], 0, 0, 0);
    acc[1] = __builtin_amdgcn_mfma_f32_16x16x32_bf16(A[q], *(const bfrag *)(wp + 512), acc[1], 0, 0, 0);
  }
}
// A-frag for ks: elements k = ks*32 + (lane>>4)*8 .. +7  == frag idx ks*4+(lane>>4)
__device__ void seg_h(f32x4 *acc, const unsigned short *hb, const short *wl,
                      int nkoff, int lane, int rbase) {
  const bfrag *ap = (const bfrag *)(hb + (size_t)(rbase + (lane & 15)) * Hc) + (lane >> 4);
  bfrag A[8], B[8];
#pragma unroll
  for (int q = 0; q < 8; ++q) A[q] = ap[(size_t)q * 4];
#pragma unroll
  for (int q = 0; q < 8; ++q) B[q] = ap[(size_t)(8 + q) * 4];
  use8(acc, A, wl, nkoff, 0, lane);
#pragma unroll
  for (int q = 0; q < 8; ++q) A[q] = ap[(size_t)(16 + q) * 4];
  use8(acc, B, wl, nkoff, 8, lane);
#pragma unroll
  for (int q = 0; q < 8; ++q) B[q] = ap[(size_t)(24 + q) * 4];
  use8(acc, A, wl, nkoff, 16, lane);
  use8(acc, B, wl, nkoff, 24, lane);
}
__device__ void seg_x(f32x4 *acc, const float *xt, const short *wl, int lane, int rbase) {
  const float4 *xp = (const float4 *)(xt + (size_t)(rbase + (lane & 15)) * Sc * Ic) + (lane >> 4) * 2;
  float4 xv[16];
#pragma unroll
  for (int q = 0; q < 8; ++q) {
    xv[2 * q]     = xp[(size_t)q * 8];
    xv[2 * q + 1] = xp[(size_t)q * 8 + 1];
  }
#pragma unroll
  for (int q = 0; q < 8; ++q) {
    bfrag av;
    const float *f0 = (const float *)&xv[2 * q];
    const float *f1 = (const float *)&xv[2 * q + 1];
#pragma unroll
    for (int e = 0; e < 4; ++e) {
      av[e]     = (short)f2b(f0[e]);
      av[4 + e] = (short)f2b(f1[e]);
    }
    const short *wp = wl + (((size_t)q * 2) * 64 + lane) * 8;
    acc[0] = __builtin_amdgcn_mfma_f32_16x16x32_bf16(av, *(const bfrag *)wp, acc[0], 0, 0, 0);
    acc[1] = __builtin_amdgcn_mfma_f32_16x16x32_bf16(av, *(const bfrag *)(wp + 512), acc[1], 0, 0, 0);
  }
}

// ---------------- epilogues (plain cached reads, sc1 writes) ----------------
__device__ void store_sig(unsigned short *out, f32x4 *acc, int c0, int lane, int rbase) {
#pragma unroll
  for (int nt = 0; nt < 2; ++nt) {
    int col = c0 + nt * 16 + (lane & 15);
#pragma unroll
    for (int j = 0; j < 4; ++j) {
      float v = 1.f / (1.f + expf(-acc[nt][j]));
      float vo = __shfl_xor(v, 1);
      if (!(lane & 1)) {
        int row = rbase + (lane >> 4) * 4 + j;
        ast32((unsigned *)out + (((size_t)row * Hc + col) >> 1),
              (unsigned)f2b(v) | ((unsigned)f2b(vo) << 16));
      }
    }
  }
}
__device__ void store_rh(unsigned short *out, const unsigned short *hb, f32x4 *acc,
                         int c0, int lane, int rbase) {
  unsigned hw[8];
#pragma unroll
  for (int nt = 0; nt < 2; ++nt)
#pragma unroll
    for (int j = 0; j < 4; ++j)
      if (!(lane & 1)) {
        int col = c0 + nt * 16 + (lane & 15);
        int row = rbase + (lane >> 4) * 4 + j;
        hw[nt * 4 + j] = *((const unsigned *)hb + (((size_t)row * Hc + col) >> 1));
      }
#pragma unroll
  for (int nt = 0; nt < 2; ++nt) {
    int col = c0 + nt * 16 + (lane & 15);
#pragma unroll
    for (int j = 0; j < 4; ++j) {
      float v = 1.f / (1.f + expf(-acc[nt][j]));
      float vo = __shfl_xor(v, 1);
      if (!(lane & 1)) {
        unsigned w = hw[nt * 4 + j];
        int row = rbase + (lane >> 4) * 4 + j;
        unsigned pk = (unsigned)f2b(v * b2f((unsigned short)(w & 0xffff)))
                    | ((unsigned)f2b(vo * b2f((unsigned short)(w >> 16))) << 16);
        ast32((unsigned *)out + (((size_t)row * Hc + col) >> 1), pk);
      }
    }
  }
}
__device__ void store_gupd(unsigned short *hnew, const unsigned short *hold,
                           const unsigned short *zb, f32x4 *acc, int c0, int lane, int rbase) {
  unsigned zw[8], hw[8];
#pragma unroll
  for (int nt = 0; nt < 2; ++nt)
#pragma unroll
    for (int j = 0; j < 4; ++j)
      if (!(lane & 1)) {
        int col = c0 + nt * 16 + (lane & 15);
        size_t iw = ((size_t)(rbase + (lane >> 4) * 4 + j) * Hc + col) >> 1;
        zw[nt * 4 + j] = *((const unsigned *)zb + iw);
        hw[nt * 4 + j] = *((const unsigned *)hold + iw);
      }
#pragma unroll
  for (int nt = 0; nt < 2; ++nt) {
    int col = c0 + nt * 16 + (lane & 15);
#pragma unroll
    for (int j = 0; j < 4; ++j) {
      float g = tanhf(acc[nt][j]);
      float go = __shfl_xor(g, 1);
      if (!(lane & 1)) {
        unsigned wz = zw[nt * 4 + j], wh = hw[nt * 4 + j];
        float zl = b2f((unsigned short)(wz & 0xffff)), zh = b2f((unsigned short)(wz >> 16));
        float hl = b2f((unsigned short)(wh & 0xffff)), hh = b2f((unsigned short)(wh >> 16));
        float hn0 = zl * hl + (1.f - zl) * g;
        float hn1 = zh * hh + (1.f - zh) * go;
        size_t iw = ((size_t)(rbase + (lane >> 4) * 4 + j) * Hc + col) >> 1;
        ast32((unsigned *)hnew + iw, (unsigned)f2b(hn0) | ((unsigned)f2b(hn1) << 16));
      }
    }
  }
}

// ---------------- weight packing --------------------------------------------
__device__ void pack_weights(short *wl, const float *W1, int K1, int ld1,
                             const float *W2, int K2, int ld2, int c0) {
  int NK = (K1 + K2) / 32;
  for (int slot = threadIdx.x; slot < NK * 128; slot += TPB) {
    int ks = slot >> 7, rem = slot & 127, nt = rem >> 6, ln = rem & 63;
    int c = c0 + nt * 16 + (ln & 15);
    int k0 = ks * 32 + (ln >> 4) * 8;
    short *dst = wl + (((size_t)ks * 2 + nt) * 64 + ln) * 8;
#pragma unroll
    for (int j = 0; j < 8; ++j) {
      int k = k0 + j;
      float w = (k < K1) ? W1[(size_t)k * ld1 + c] : W2[(size_t)(k - K1) * ld2 + c];
      dst[j] = (short)f2b(w);
    }
  }
}

// ---------------- main ------------------------------------------------------
__global__ void __launch_bounds__(TPB) gru_df(Args a) {
  extern __shared__ short wl[];
  const int wg = blockIdx.x, tid = threadIdx.x;
  const int lane = tid & 63, wid = tid >> 6, rbase = wid * 16;
  const int gate = (wg < 32) ? 0 : (wg < 64) ? 1 : (wg < 96) ? 2 :
                   (wg < 128) ? 3 : (wg < 160) ? 4 : (wg < 192) ? 5 : 6;
  const int c0 = (gate == 6) ? (wg - 192) * 32 : (wg - gate * 32) * 32;
  static const int K1tab[7] = {256, 256, 256, 1024, 1024, 1024, 1024};
  static const int K2tab[7] = {1024, 1024, 1024, 1024, 1024, 1024, 0};
  const int ld1 = (gate == 6) ? Oc : Hc;

  pack_weights(wl, a.W1[gate], K1tab[gate], ld1, a.W2[gate], K2tab[gate], Hc, c0);

  // per-thread poll assignment: (slot, threshold offset); thr = t + off
  int pslot = -1, poff = 0;
  if (gate <= 1) {
    if (tid < 32) { pslot = 64 + tid; poff = 1; }                 // g0
  } else if (gate == 2) {
    if (tid < 64)       { pslot = tid;              poff = 2; }   // zr0
    else if (tid < 128) { pslot = 96 + (tid - 64);  poff = 0; }   // zr1 (WAR)
    else if (tid < 160) { pslot = 160 + (tid - 128); poff = 0; }  // g1 (WAR)
  } else if (gate <= 4) {
    if (tid < 32)      { pslot = 64 + tid;          poff = 2; }   // g0
    else if (tid < 64) { pslot = 160 + (tid - 32);  poff = 1; }   // g1
  } else if (gate == 5) {
    if (tid < 64)       { pslot = 96 + tid;         poff = 2; }   // zr1
    else if (tid < 96)  { pslot = 64 + (tid - 64);  poff = 2; }   // g0
    else if (tid < 104) { pslot = 192 + (tid - 96); poff = 0; }   // y (WAR)
  } else {
    if (tid < 32) { pslot = 160 + tid; poff = 2; }                // g1
  }

  // init h(-1) into buf1 (h0[1], h1[1]), packed bf16 via sc1 stores
  for (int u = wg * TPB + tid; u < Bc * Hc / 2; u += NWG * TPB) {
    int b = u >> 9, hp = (u & 511) * 2;
    const float *s0 = a.h0in + (size_t)(b * 2) * Hc + hp;
    const float *s1 = a.h0in + (size_t)(b * 2 + 1) * Hc + hp;
    ast32((unsigned *)a.h0[1] + u, (unsigned)f2b(s0[0]) | ((unsigned)f2b(s0[1]) << 16));
    ast32((unsigned *)a.h1[1] + u, (unsigned)f2b(s1[0]) | ((unsigned)f2b(s1[1]) << 16));
  }
  stamp(a.sl, wg, 1);
  waitslots(a.sl, (tid < NWG) ? tid : -1, 1);

  const float *bias = a.bias[gate];

  if (gate <= 1) {                                   // ---- zr0
    for (int t = 0; t < Sc; ++t) {
      waitslots(a.sl, pslot, (pslot >= 0) ? t + poff : 0);
      const unsigned short *h0c = a.h0[(t + 1) & 1];             // h0(t-1)
      float b0 = bias[c0 + (lane & 15)], b1 = bias[c0 + 16 + (lane & 15)];
      f32x4 acc[2] = {{b0, b0, b0, b0}, {b1, b1, b1, b1}};
      seg_x(acc, a.x + (size_t)t * Ic, wl, lane, rbase);
      seg_h(acc, h0c, wl, 8, lane, rbase);
      if (gate == 0) store_sig(a.z0[t & 1], acc, c0, lane, rbase);
      else           store_rh(a.rh0[t & 1], h0c, acc, c0, lane, rbase);
      stamp(a.sl, wg, t + 2);
    }
  } else if (gate == 2) {                            // ---- g0
    for (int t = 0; t < Sc; ++t) {
      waitslots(a.sl, pslot, (pslot >= 0) ? t + poff : 0);
      const unsigned short *h0c = a.h0[(t + 1) & 1];
      unsigned short *h0n = a.h0[t & 1];                          // h0(t)
      float b0 = bias[c0 + (lane & 15)], b1 = bias[c0 + 16 + (lane & 15)];
      f32x4 acc[2] = {{b0, b0, b0, b0}, {b1, b1, b1, b1}};
      seg_x(acc, a.x + (size_t)t * Ic, wl, lane, rbase);
      seg_h(acc, a.rh0[t & 1], wl, 8, lane, rbase);
      store_gupd(h0n, h0c, a.z0[t & 1], acc, c0, lane, rbase);
      stamp(a.sl, wg, t + 2);
    }
    // hs epilogue: final h0(1023), h1(1023) in buf1
    {
      int eslot = -1;
      if (tid < 32) eslot = 64 + tid;
      else if (tid < 64) eslot = 160 + (tid - 32);
      waitslots(a.sl, eslot, Sc + 1);
    }
    for (int k = (wg - 64) * TPB + tid; k < Bc * 2 * Hc; k += 32 * TPB) {
      int b = k >> 11, l = (k >> 10) & 1, h = k & 1023;
      const unsigned short *src = l ? a.h1[1] : a.h0[1];
      a.hs[k] = b2f(src[(size_t)b * Hc + h]);
    }
  } else if (gate <= 4) {                            // ---- zr1
    for (int t = 0; t < Sc; ++t) {
      waitslots(a.sl, pslot, (pslot >= 0) ? t + poff : 0);
      const unsigned short *h0n = a.h0[t & 1];                    // h0(t)
      const unsigned short *h1c = a.h1[(t + 1) & 1];              // h1(t-1)
      float b0 = bias[c0 + (lane & 15)], b1 = bias[c0 + 16 + (lane & 15)];
      f32x4 acc[2] = {{b0, b0, b0, b0}, {b1, b1, b1, b1}};
      seg_h(acc, h0n, wl, 0, lane, rbase);
      seg_h(acc, h1c, wl, 32, lane, rbase);
      if (gate == 3) store_sig(a.z1[t & 1], acc, c0, lane, rbase);
      else           store_rh(a.rh1[t & 1], h1c, acc, c0, lane, rbase);
      stamp(a.sl, wg, t + 2);
    }
  } else if (gate == 5) {                            // ---- g1
    for (int t = 0; t < Sc; ++t) {
      waitslots(a.sl, pslot, (pslot >= 0) ? t + poff : 0);
      const unsigned short *h0n = a.h0[t & 1];
      const unsigned short *h1c = a.h1[(t + 1) & 1];
      unsigned short *h1n = a.h1[t & 1];                          // h1(t)
      float b0 = bias[c0 + (lane & 15)], b1 = bias[c0 + 16 + (lane & 15)];
      f32x4 acc[2] = {{b0, b0, b0, b0}, {b1, b1, b1, b1}};
      seg_h(acc, h0n, wl, 0, lane, rbase);
      seg_h(acc, a.rh1[t & 1], wl, 32, lane, rbase);
      store_gupd(h1n, h1c, a.z1[t & 1], acc, c0, lane, rbase);
      stamp(a.sl, wg, t + 2);
    }
  } else {                                           // ---- y
    for (int t = 0; t < Sc; ++t) {
      waitslots(a.sl, pslot, (pslot >= 0) ? t + poff : 0);
      const unsigned short *h1t = a.h1[t & 1];                    // h1(t)
      float b0 = bias[c0 + (lane & 15)], b1 = bias[c0 + 16 + (lane & 15)];
      f32x4 acc[2] = {{b0, b0, b0, b0}, {b1, b1, b1, b1}};
      seg_h(acc, h1t, wl, 0, lane, rbase);
#pragma unroll
      for (int nt = 0; nt < 2; ++nt) {
        int col = c0 + nt * 16 + (lane & 15);
#pragma unroll
        for (int j = 0; j < 4; ++j) {
          int row = rbase + (lane >> 4) * 4 + j;
          a.y[((size_t)row * Sc + t) * Oc + col] = acc[nt][j];
        }
      }
      stamp(a.sl, wg, t + 2);
    }
  }
}

extern "C" void kernel_launch(void *const *d_in, const int *in_sizes, int n_in,
                              void *d_out, int out_size, void *d_ws, size_t ws_size,
                              hipStream_t stream) {
  (void)in_sizes; (void)n_in; (void)out_size; (void)ws_size;
  Args a;
  a.x    = (const float *)d_in[0];
  a.h0in = (const float *)d_in[1];
  a.W1[0] = (const float *)d_in[2];  a.W2[0] = (const float *)d_in[5];  a.bias[0] = (const float *)d_in[6];
  a.W1[1] = (const float *)d_in[3];  a.W2[1] = (const float *)d_in[7];  a.bias[1] = (const float *)d_in[8];
  a.W1[2] = (const float *)d_in[4];  a.W2[2] = (const float *)d_in[9];  a.bias[2] = (const float *)d_in[10];
  a.W1[3] = (const float *)d_in[11]; a.W2[3] = (const float *)d_in[14]; a.bias[3] = (const float *)d_in[15];
  a.W1[4] = (const float *)d_in[12]; a.W2[4] = (const float *)d_in[16]; a.bias[4] = (const float *)d_in[17];
  a.W1[5] = (const float *)d_in[13]; a.W2[5] = (const float *)d_in[18]; a.bias[5] = (const float *)d_in[19];
  a.W1[6] = (const float *)d_in[20]; a.W2[6] = nullptr;                 a.bias[6] = (const float *)d_in[21];

  char *w = (char *)d_ws;
  a.h0[0]  = (unsigned short *)(w + 0);
  a.h0[1]  = (unsigned short *)(w + 131072);
  a.h1[0]  = (unsigned short *)(w + 262144);
  a.h1[1]  = (unsigned short *)(w + 393216);
  a.z0[0]  = (unsigned short *)(w + 524288);
  a.z0[1]  = (unsigned short *)(w + 655360);
  a.rh0[0] = (unsigned short *)(w + 786432);
  a.rh0[1] = (unsigned short *)(w + 917504);
  a.z1[0]  = (unsigned short *)(w + 1048576);
  a.z1[1]  = (unsigned short *)(w + 1179648);
  a.rh1[0] = (unsigned short *)(w + 1310720);
  a.rh1[1] = (unsigned short *)(w + 1441792);
  a.sl     = (unsigned *)(w + 1572864);
  a.y   = (float *)d_out;
  a.hs  = a.y + (size_t)Bc * Sc * Oc;

  (void)hipMemsetAsync(a.sl, 0, 32768, stream);
  (void)hipFuncSetAttribute((const void *)gru_df,
                            hipFuncAttributeMaxDynamicSharedMemorySize, 131072);
  gru_df<<<NWG, TPB, 131072, stream>>>(a);
}